// Round 1
// baseline (577.722 us; speedup 1.0000x reference)
//
#include <hip/hip_runtime.h>
#include <stdint.h>

#define NPER  25000
#define NNODE 50000
#define NEDGE 600000
#define NREL  8
#define NBASE 4
#define INDIM 256
#define HIDD  128
#define OUTD  64
#define NSEG  (NNODE * NREL)

typedef unsigned short u16;
typedef unsigned int   u32;
typedef __attribute__((ext_vector_type(8))) __bf16          bf16x8;
typedef __attribute__((ext_vector_type(8))) unsigned short  ushort8;
typedef __attribute__((ext_vector_type(4))) float           f32x4;

__device__ __forceinline__ u16 f2b(float f) {
    union { __bf16 h; u16 u; } v; v.h = (__bf16)f; return v.u;   // HW RNE cvt
}
__device__ __forceinline__ bf16x8 as_bf(ushort8 u) {
    union { ushort8 a; bf16x8 b; } v; v.a = u; return v.b;
}
__device__ __forceinline__ bf16x8 cvt8(const float* p) {
    f32x4 f0 = *(const f32x4*)p;
    f32x4 f1 = *(const f32x4*)(p + 4);
    ushort8 u;
#pragma unroll
    for (int i = 0; i < 4; i++) { u[i] = f2b(f0[i]); u[i + 4] = f2b(f1[i]); }
    return as_bf(u);
}
__device__ __forceinline__ float blo(u32 v) {
    union { u32 i; float f; } u; u.i = v << 16; return u.f;
}
__device__ __forceinline__ float bhi(u32 v) {
    union { u32 i; float f; } u; u.i = v & 0xffff0000u; return u.f;
}

// ---------------- fused weight repack: all 5 Bsw buffers in ONE kernel ----------------
// Bsw[((ks*NT + nt) << 9) + lane*8 + j] = W[k][col],
//   k = ks*32 + (lane>>4)*8 + j, col = nt*16 + (lane&15).
__device__ __forceinline__ void bsw_proj_elem(const float* __restrict__ W, u16* __restrict__ out, int idx) {
    int j    = idx & 7;
    int lane = (idx >> 3) & 63;
    int rest = idx >> 9;
    int nt   = rest & 7;           // 128/16 = 8 col tiles
    int ks   = rest >> 3;
    int col  = nt * 16 + (lane & 15);
    int k    = ks * 32 + ((lane >> 4) << 3) + j;
    out[idx] = f2b(W[(size_t)k * 128 + col]);
}
__device__ __forceinline__ void bsw_conv_elem(const float* __restrict__ bases, const float* __restrict__ root,
                                              int ncol, u16* __restrict__ out, int idx) {
    int nt_cnt = ncol >> 4;
    int j    = idx & 7;
    int lane = (idx >> 3) & 63;
    int rest = idx >> 9;
    int nt   = rest % nt_cnt;
    int ks   = rest / nt_cnt;
    int col  = nt * 16 + (lane & 15);
    int k    = ks * 32 + ((lane >> 4) << 3) + j;
    float v = (k < 512) ? bases[(size_t)k * ncol + col] : root[(size_t)(k - 512) * ncol + col];
    out[idx] = f2b(v);
}
// block ranges: [0,128) Wp | [128,256) Wa | [256,576) conv0 | [576,896) conv1 | [896,1056) conv2
__global__ void build_bsw_all(const float* __restrict__ Wp, const float* __restrict__ Wa,
                              const float* __restrict__ bases0, const float* __restrict__ root0,
                              const float* __restrict__ bases1, const float* __restrict__ root1,
                              const float* __restrict__ bases2, const float* __restrict__ root2,
                              u16* __restrict__ Bswp, u16* __restrict__ Bswa,
                              u16* __restrict__ Bswc0, u16* __restrict__ Bswc1, u16* __restrict__ Bswc2) {
    int b = blockIdx.x, t = threadIdx.x;
    if (b < 128)       bsw_proj_elem(Wp, Bswp, b * 256 + t);
    else if (b < 256)  bsw_proj_elem(Wa, Bswa, (b - 128) * 256 + t);
    else if (b < 576)  bsw_conv_elem(bases0, root0, HIDD, Bswc0, (b - 256) * 256 + t);
    else if (b < 896)  bsw_conv_elem(bases1, root1, HIDD, Bswc1, (b - 576) * 256 + t);
    else               bsw_conv_elem(bases2, root2, OUTD, Bswc2, (b - 896) * 256 + t);
}

// ---------------- CSR build over seg = dst*8 + etype ----------------
__global__ void hist_kernel(const int* __restrict__ ei, const int* __restrict__ et,
                            int* __restrict__ cnt) {
    int e = blockIdx.x * blockDim.x + threadIdx.x;
    if (e >= NEDGE) return;
    int dst = ei[NEDGE + e];
    int r   = et[e];
    atomicAdd(&cnt[dst * NREL + r], 1);
}

#define SCAN_CHUNK 1024
__global__ void scan1_kernel(int* __restrict__ data, int n, int* __restrict__ bsum) {
    __shared__ int sh[256];
    int t = threadIdx.x;
    int base = blockIdx.x * SCAN_CHUNK + t * 4;
    int v[4];
#pragma unroll
    for (int i = 0; i < 4; i++) v[i] = (base + i < n) ? data[base + i] : 0;
    int tot = v[0] + v[1] + v[2] + v[3];
    sh[t] = tot; __syncthreads();
    for (int off = 1; off < 256; off <<= 1) {
        int x = (t >= off) ? sh[t - off] : 0;
        __syncthreads();
        sh[t] += x;
        __syncthreads();
    }
    int excl = sh[t] - tot;
    if (t == 255) bsum[blockIdx.x] = sh[255];
    int run = excl;
#pragma unroll
    for (int i = 0; i < 4; i++) {
        if (base + i < n) data[base + i] = run;
        run += v[i];
    }
}

__global__ void scan2_kernel(int* __restrict__ bsum, int nb) {
    __shared__ int sh[512];
    int t = threadIdx.x;
    int v = (t < nb) ? bsum[t] : 0;
    sh[t] = v; __syncthreads();
    for (int off = 1; off < 512; off <<= 1) {
        int x = (t >= off) ? sh[t - off] : 0;
        __syncthreads();
        sh[t] += x;
        __syncthreads();
    }
    if (t < nb) bsum[t] = sh[t] - v;
}

// also materializes fill[] (scatter cursor) — drops the d2d memcpy dispatch
__global__ void scan3_kernel(int* __restrict__ data, int n, const int* __restrict__ bsum,
                             int* __restrict__ fill) {
    int add = bsum[blockIdx.x];
    int base = blockIdx.x * SCAN_CHUNK + threadIdx.x * 4;
#pragma unroll
    for (int i = 0; i < 4; i++) {
        int idx = base + i;
        if (idx < n) {
            int v = data[idx] + add;
            data[idx] = v;
            if (idx < NSEG) fill[idx] = v;
        }
    }
}

// packs (src | rel<<16) so agg can walk a node's edges as ONE contiguous run
__global__ void scatter_kernel(const int* __restrict__ ei, const int* __restrict__ et,
                               int* __restrict__ fill, int* __restrict__ epk) {
    int e = blockIdx.x * blockDim.x + threadIdx.x;
    if (e >= NEDGE) return;
    int src = ei[e];
    int dst = ei[NEDGE + e];
    int r   = et[e];
    int pos = atomicAdd(&fill[dst * NREL + r], 1);
    epk[pos] = src | (r << 16);
}

// ---------------- FUSED conv: mean-aggregate + comp contraction + MFMA GEMM ----------------
// One block = 64 nodes = one GEMM M-tile. 4 waves x 16 nodes each.
// Phase 1 (agg): per node, walk (dst,rel)-sorted edge run (4-deep pipelined gather,
//   sentinel rel=8 -> zero weight via readlane from zeroed lanes 32..35), accumulate
//   4 bases x 2 channels per lane, write bf16 row to LDS with XOR swizzle
//   byte ^= (row&7)<<4 so phase-2 ds_read_b128 A-frags are bank-conflict-free.
// Phase 2 (gemm): A[64 x 512] from LDS + A-tail[64 x 128] (root term) from xbf global;
//   B fragment-swizzled (Bsw); 16x16x32 bf16 MFMA; epilogue bias/relu/residual.
// Saves the 51.2 MB Abuf write + 51.2 MB read per conv vs the split kernels.
template<int NT, bool RELU, bool RES>
__global__ __launch_bounds__(256, 2) void fused_conv(
    const u16* __restrict__ xbf, const float* __restrict__ comp,
    const int* __restrict__ rowptr, const int* __restrict__ epk,
    const u16* __restrict__ Bsw, const float* __restrict__ bias,
    float* __restrict__ out1, u16* __restrict__ outb,
    const float* __restrict__ resid, int ldo) {
    __shared__ u16 As[64 * 512];           // 64 KB: 64 rows x 512 bf16 (4 bases x 128 ch)
    int tid  = threadIdx.x;
    int wv   = __builtin_amdgcn_readfirstlane(tid >> 6);
    int lane = tid & 63;
    int co   = lane * 2;                   // u16 offset within 128-ch row
    float compv = (lane < 32) ? comp[lane] : 0.f;   // lanes >=32 hold 0 (sentinel slot)
    const int INV = 8 << 16;               // sentinel: src=0, rel=8 (zero weight)

    // ---- phase 1: aggregate 16 nodes per wave into LDS ----
    for (int i = 0; i < 16; i++) {
        int node = blockIdx.x * 64 + wv * 16 + i;
        int lr   = wv * 16 + i;            // local row in tile
        float a0[4] = {0.f, 0.f, 0.f, 0.f};
        float a1[4] = {0.f, 0.f, 0.f, 0.f};
        int p = 0, e = 0;
        float wl = 0.f;                    // lane k<32 holds comp[r][b]*norm(r), r=k>>2, b=k&3
        if (node < NNODE) {
            int rbase = node * NREL;
            if (lane < 32) {
                int r   = lane >> 2;
                int c0  = rowptr[rbase + r], c1 = rowptr[rbase + r + 1];
                int cnt = c1 - c0;
                float nrm = (cnt > 0) ? 1.f / (float)cnt : 0.f;
                wl = compv * nrm;
            }
            p = __builtin_amdgcn_readfirstlane(rowptr[rbase]);
            e = __builtin_amdgcn_readfirstlane(rowptr[rbase + 8]);
        }
        int k0[4]; u32 v0[4];
#pragma unroll
        for (int j = 0; j < 4; j++) k0[j] = (p + j < e) ? epk[p + j] : INV;
#pragma unroll
        for (int j = 0; j < 4; j++) v0[j] = *(const u32*)(xbf + ((size_t)(k0[j] & 0xffff) << 7) + co);
        for (int pc = p; pc < e; pc += 4) {
            int pn = pc + 4;
            int k1[4]; u32 v1[4];
#pragma unroll
            for (int j = 0; j < 4; j++) k1[j] = (pn + j < e) ? epk[pn + j] : INV;
#pragma unroll
            for (int j = 0; j < 4; j++) v1[j] = *(const u32*)(xbf + ((size_t)(k1[j] & 0xffff) << 7) + co);
#pragma unroll
            for (int j = 0; j < 4; j++) {
                int ri = __builtin_amdgcn_readfirstlane((k0[j] >> 16) << 2);   // rel uniform per edge
                float w0 = __uint_as_float(__builtin_amdgcn_readlane(__float_as_uint(wl), ri));
                float w1 = __uint_as_float(__builtin_amdgcn_readlane(__float_as_uint(wl), ri + 1));
                float w2 = __uint_as_float(__builtin_amdgcn_readlane(__float_as_uint(wl), ri + 2));
                float w3 = __uint_as_float(__builtin_amdgcn_readlane(__float_as_uint(wl), ri + 3));
                float xl = blo(v0[j]), xh = bhi(v0[j]);
                a0[0] += w0 * xl; a1[0] += w0 * xh;
                a0[1] += w1 * xl; a1[1] += w1 * xh;
                a0[2] += w2 * xl; a1[2] += w2 * xh;
                a0[3] += w3 * xl; a1[3] += w3 * xh;
            }
#pragma unroll
            for (int j = 0; j < 4; j++) { k0[j] = k1[j]; v0[j] = v1[j]; }
        }
        // write row lr: k = b*128 + 2*lane (+1); raw byte = k*2 = b*256 + lane*4, XOR-swizzled
        u32 swz = (u32)(lr & 7) << 4;
        char* rowp = (char*)As + lr * 1024;
#pragma unroll
        for (int b = 0; b < 4; b++) {
            u32 pk = (u32)f2b(a0[b]) | ((u32)f2b(a1[b]) << 16);
            *(u32*)(rowp + (((u32)(b * 256 + lane * 4)) ^ swz)) = pk;
        }
    }
    __syncthreads();

    // ---- phase 2: [64 x 640] @ [640 x NT*16] MFMA ----
    int l15 = lane & 15, quad = lane >> 4;
    int rowbase = blockIdx.x * 64 + wv * 16;       // wave owns 16 rows x NT*16 cols
    int xrow = rowbase + l15; if (xrow > NNODE - 1) xrow = NNODE - 1;
    const u16*  bp   = Bsw + lane * 8;
    const char* arow = (const char*)As + (wv * 16 + l15) * 1024;
    u32 swz2 = (u32)(l15 & 7) << 4;
    f32x4 acc[NT];
#pragma unroll
    for (int nt = 0; nt < NT; nt++) acc[nt] = (f32x4){0.f, 0.f, 0.f, 0.f};
#pragma unroll
    for (int ks = 0; ks < 20; ks++) {
        bf16x8 a;
        if (ks < 16) a = *(const bf16x8*)(arow + (((u32)(ks * 64 + quad * 16)) ^ swz2));
        else         a = as_bf(*(const ushort8*)(xbf + (size_t)xrow * 128 + (ks - 16) * 32 + quad * 8));
#pragma unroll
        for (int nt = 0; nt < NT; nt++) {
            bf16x8 b = as_bf(*(const ushort8*)(bp + ((size_t)(ks * NT + nt) << 9)));
            acc[nt] = __builtin_amdgcn_mfma_f32_16x16x32_bf16(a, b, acc[nt], 0, 0, 0);
        }
    }
    int orow0 = rowbase + quad * 4;
#pragma unroll
    for (int r = 0; r < 4; r++) {
        int orow = orow0 + r;
        if (orow < NNODE) {
#pragma unroll
            for (int nt = 0; nt < NT; nt++) {
                int col = nt * 16 + l15;
                float v = acc[nt][r] + bias[col];
                if (RELU) v = v > 0.f ? v : 0.f;
                if (RES)  v += resid[(size_t)orow * ldo + col];
                size_t oi = (size_t)orow * ldo + col;
                if (out1) out1[oi] = v;
                if (outb) outb[oi] = f2b(v);
            }
        }
    }
}

// ---------------- MFMA bf16 GEMM core (projections) ----------------
template<int KMAIN, bool HASX, int NW, int MW, int NT, bool RELU, bool RES, bool AF32>
__device__ __forceinline__ void gemm_core(
    int blk, const void* __restrict__ Av, const u16* __restrict__ xq,
    const u16* __restrict__ Bsw, const float* __restrict__ bias, int M,
    float* __restrict__ out1, float* __restrict__ out2, u16* __restrict__ outb,
    const float* __restrict__ resid, int ldo) {
    constexpr int KSM = KMAIN / 32;
    constexpr int KST = KSM + (HASX ? 4 : 0);
    int tid  = threadIdx.x;
    int wave = tid >> 6, lane = tid & 63;
    int l15  = lane & 15, quad = lane >> 4;
    int rowbase = blk * (NW * MW * 16) + wave * (MW * 16);
    int rA[MW];
#pragma unroll
    for (int m = 0; m < MW; m++) {
        rA[m] = rowbase + m * 16 + l15;
        if (rA[m] > M - 1) rA[m] = M - 1;
    }
    const u16* bp = Bsw + lane * 8;
    f32x4 acc[MW][NT];
#pragma unroll
    for (int m = 0; m < MW; m++)
#pragma unroll
        for (int i = 0; i < NT; i++) acc[m][i] = (f32x4){0.f, 0.f, 0.f, 0.f};
#pragma unroll
    for (int ks = 0; ks < KST; ks++) {
        bf16x8 a[MW];
#pragma unroll
        for (int m = 0; m < MW; m++) {
            if (ks < KSM) {
                if (AF32) a[m] = cvt8((const float*)Av + (size_t)rA[m] * KMAIN + ks * 32 + quad * 8);
                else      a[m] = as_bf(*(const ushort8*)((const u16*)Av + (size_t)rA[m] * KMAIN + ks * 32 + quad * 8));
            } else {
                a[m] = as_bf(*(const ushort8*)(xq + (size_t)rA[m] * 128 + (ks - KSM) * 32 + quad * 8));
            }
        }
#pragma unroll
        for (int nt = 0; nt < NT; nt++) {
            bf16x8 b = as_bf(*(const ushort8*)(bp + ((size_t)(ks * NT + nt) << 9)));
#pragma unroll
            for (int m = 0; m < MW; m++)
                acc[m][nt] = __builtin_amdgcn_mfma_f32_16x16x32_bf16(a[m], b, acc[m][nt], 0, 0, 0);
        }
    }
#pragma unroll
    for (int m = 0; m < MW; m++) {
        int orow0 = rowbase + m * 16 + quad * 4;
#pragma unroll
        for (int r = 0; r < 4; r++) {
            int orow = orow0 + r;
            if (orow < M) {
#pragma unroll
                for (int nt = 0; nt < NT; nt++) {
                    int col = nt * 16 + l15;
                    float v = acc[m][nt][r] + bias[col];
                    if (RELU) v = v > 0.f ? v : 0.f;
                    if (RES)  v += resid[(size_t)orow * ldo + col];
                    size_t oi = (size_t)orow * ldo + col;
                    if (out1) out1[oi] = v;
                    if (out2) out2[oi] = v;
                    if (outb) outb[oi] = f2b(v);
                }
            }
        }
    }
}

// both projections in one dispatch (gridDim.y = 2 selects paper/author)
__global__ __launch_bounds__(256, 2) void proj2_kernel(
    const float* __restrict__ xp, const float* __restrict__ xa,
    const u16* __restrict__ Bswp, const u16* __restrict__ Bswa,
    const float* __restrict__ bp, const float* __restrict__ ba,
    float* __restrict__ lat0, float* __restrict__ lat1, u16* __restrict__ xbf0) {
    int y = blockIdx.y;
    const float* A    = y ? xa : xp;
    const u16*   B    = y ? Bswa : Bswp;
    const float* bias = y ? ba : bp;
    size_t off = (size_t)y * NPER * HIDD;
    gemm_core<256, false, 4, 1, 8, true, false, true>(
        blockIdx.x, A, nullptr, B, bias, NPER, lat0 + off, lat1 + off, xbf0 + off, nullptr, HIDD);
}

extern "C" void kernel_launch(void* const* d_in, const int* in_sizes, int n_in,
                              void* d_out, int out_size, void* d_ws, size_t ws_size,
                              hipStream_t stream) {
    const float* x_paper  = (const float*)d_in[0];
    const float* x_author = (const float*)d_in[1];
    const float* W_paper  = (const float*)d_in[2];
    const float* b_paper  = (const float*)d_in[3];
    const float* W_author = (const float*)d_in[4];
    const float* b_author = (const float*)d_in[5];
    const float* bases0   = (const float*)d_in[6];
    const float* comp0    = (const float*)d_in[7];
    const float* root0    = (const float*)d_in[8];
    const float* bias0    = (const float*)d_in[9];
    const float* bases1   = (const float*)d_in[10];
    const float* comp1    = (const float*)d_in[11];
    const float* root1    = (const float*)d_in[12];
    const float* bias1    = (const float*)d_in[13];
    const float* bases2   = (const float*)d_in[14];
    const float* comp2    = (const float*)d_in[15];
    const float* root2    = (const float*)d_in[16];
    const float* bias2    = (const float*)d_in[17];
    const int* ei         = (const int*)d_in[18];
    const int* et         = (const int*)d_in[19];

    float* ob   = (float*)d_out;
    float* outF = ob;                         // [50000,64]
    float* lat0 = ob + 3200000;               // x0
    float* lat1 = ob + 9600000;               // x0 (copy)
    float* lat2 = ob + 16000000;              // x1

    char* w = (char*)d_ws;
    u16*   xbf0   = (u16*)(w + 51200000);     // 12,800,000
    u16*   xbf1   = (u16*)(w + 64000000);     // 12,800,000
    u16*   Bswc0  = (u16*)(w + 76800000);     // 163,840
    u16*   Bswc1  = (u16*)(w + 76963840);     // 163,840
    u16*   Bswc2  = (u16*)(w + 77127680);     // 81,920
    u16*   Bswp   = (u16*)(w + 77209600);     // 65,536
    u16*   Bswa   = (u16*)(w + 77275136);     // 65,536
    int*   rowptr = (int*)(w + 77340672);     // 400001*4 (pad to 1,600,064)
    int*   fill   = (int*)(w + 78940736);     // 1,600,000
    int*   epk    = (int*)(w + 80540736);     // 2,400,000
    int*   bsum   = (int*)(w + 82940736);     // 2,048

    // ---- all weight repacks, one dispatch ----
    build_bsw_all<<<1056, 256, 0, stream>>>(W_paper, W_author, bases0, root0,
                                            bases1, root1, bases2, root2,
                                            Bswp, Bswa, Bswc0, Bswc1, Bswc2);

    // ---- projections: x0 = relu(x @ W + b) -> lat0, lat1 (fp32) + xbf0 (bf16) ----
    proj2_kernel<<<dim3((NPER + 63) / 64, 2), 256, 0, stream>>>(
        x_paper, x_author, Bswp, Bswa, b_paper, b_author, lat0, lat1, xbf0);

    // ---- CSR over (dst, rel) segments (shared by all 3 convs) ----
    hipMemsetAsync(rowptr, 0, (NSEG + 1) * sizeof(int), stream);
    hist_kernel<<<(NEDGE + 255) / 256, 256, 0, stream>>>(ei, et, rowptr);
    int nchunk = (NSEG + 1 + SCAN_CHUNK - 1) / SCAN_CHUNK;   // 391
    scan1_kernel<<<nchunk, 256, 0, stream>>>(rowptr, NSEG + 1, bsum);
    scan2_kernel<<<1, 512, 0, stream>>>(bsum, nchunk);
    scan3_kernel<<<nchunk, 256, 0, stream>>>(rowptr, NSEG + 1, bsum, fill);
    scatter_kernel<<<(NEDGE + 255) / 256, 256, 0, stream>>>(ei, et, fill, epk);

    int ngrid = (NNODE + 63) / 64;            // 782 blocks, 64 nodes each

    // ---- conv0: x1 = relu(rgcn(x0)) -> lat2 (fp32) + xbf1 (bf16) ----
    fused_conv<8, true, false><<<ngrid, 256, 0, stream>>>(
        xbf0, comp0, rowptr, epk, Bswc0, bias0, lat2, xbf1, nullptr, HIDD);

    // ---- conv1: x2 = x1 + relu(rgcn(x1)) -> xbf0 (bf16 only; x2 not an output) ----
    fused_conv<8, true, true><<<ngrid, 256, 0, stream>>>(
        xbf1, comp1, rowptr, epk, Bswc1, bias1, nullptr, xbf0, lat2, HIDD);

    // ---- conv2: out = rgcn(x2) (no relu) -> outF fp32 ----
    fused_conv<4, false, false><<<ngrid, 256, 0, stream>>>(
        xbf0, comp2, rowptr, epk, Bswc2, bias2, outF, nullptr, nullptr, OUTD);
}

// Round 2
// 397.325 us; speedup vs baseline: 1.4540x; 1.4540x over previous
//
#include <hip/hip_runtime.h>
#include <stdint.h>

#define NPER  25000
#define NNODE 50000
#define NEDGE 600000
#define NREL  8
#define NBASE 4
#define INDIM 256
#define HIDD  128
#define OUTD  64
#define NSEG  (NNODE * NREL)

typedef unsigned short u16;
typedef unsigned int   u32;
typedef __attribute__((ext_vector_type(8))) __bf16          bf16x8;
typedef __attribute__((ext_vector_type(8))) unsigned short  ushort8;
typedef __attribute__((ext_vector_type(4))) float           f32x4;

__device__ __forceinline__ u16 f2b(float f) {
    union { __bf16 h; u16 u; } v; v.h = (__bf16)f; return v.u;   // HW RNE cvt
}
__device__ __forceinline__ bf16x8 as_bf(ushort8 u) {
    union { ushort8 a; bf16x8 b; } v; v.a = u; return v.b;
}
__device__ __forceinline__ bf16x8 cvt8(const float* p) {
    f32x4 f0 = *(const f32x4*)p;
    f32x4 f1 = *(const f32x4*)(p + 4);
    ushort8 u;
#pragma unroll
    for (int i = 0; i < 4; i++) { u[i] = f2b(f0[i]); u[i + 4] = f2b(f1[i]); }
    return as_bf(u);
}
__device__ __forceinline__ float blo(u32 v) {
    union { u32 i; float f; } u; u.i = v << 16; return u.f;
}
__device__ __forceinline__ float bhi(u32 v) {
    union { u32 i; float f; } u; u.i = v & 0xffff0000u; return u.f;
}

// ---------------- fused weight repack: all 5 Bsw buffers in ONE kernel ----------------
// Bsw[((ks*NT + nt) << 9) + lane*8 + j] = W[k][col],
//   k = ks*32 + (lane>>4)*8 + j, col = nt*16 + (lane&15).
__device__ __forceinline__ void bsw_proj_elem(const float* __restrict__ W, u16* __restrict__ out, int idx) {
    int j    = idx & 7;
    int lane = (idx >> 3) & 63;
    int rest = idx >> 9;
    int nt   = rest & 7;           // 128/16 = 8 col tiles
    int ks   = rest >> 3;
    int col  = nt * 16 + (lane & 15);
    int k    = ks * 32 + ((lane >> 4) << 3) + j;
    out[idx] = f2b(W[(size_t)k * 128 + col]);
}
__device__ __forceinline__ void bsw_conv_elem(const float* __restrict__ bases, const float* __restrict__ root,
                                              int ncol, u16* __restrict__ out, int idx) {
    int nt_cnt = ncol >> 4;
    int j    = idx & 7;
    int lane = (idx >> 3) & 63;
    int rest = idx >> 9;
    int nt   = rest % nt_cnt;
    int ks   = rest / nt_cnt;
    int col  = nt * 16 + (lane & 15);
    int k    = ks * 32 + ((lane >> 4) << 3) + j;
    float v = (k < 512) ? bases[(size_t)k * ncol + col] : root[(size_t)(k - 512) * ncol + col];
    out[idx] = f2b(v);
}
// block ranges: [0,128) Wp | [128,256) Wa | [256,576) conv0 | [576,896) conv1 | [896,1056) conv2
__global__ void build_bsw_all(const float* __restrict__ Wp, const float* __restrict__ Wa,
                              const float* __restrict__ bases0, const float* __restrict__ root0,
                              const float* __restrict__ bases1, const float* __restrict__ root1,
                              const float* __restrict__ bases2, const float* __restrict__ root2,
                              u16* __restrict__ Bswp, u16* __restrict__ Bswa,
                              u16* __restrict__ Bswc0, u16* __restrict__ Bswc1, u16* __restrict__ Bswc2) {
    int b = blockIdx.x, t = threadIdx.x;
    if (b < 128)       bsw_proj_elem(Wp, Bswp, b * 256 + t);
    else if (b < 256)  bsw_proj_elem(Wa, Bswa, (b - 128) * 256 + t);
    else if (b < 576)  bsw_conv_elem(bases0, root0, HIDD, Bswc0, (b - 256) * 256 + t);
    else if (b < 896)  bsw_conv_elem(bases1, root1, HIDD, Bswc1, (b - 576) * 256 + t);
    else               bsw_conv_elem(bases2, root2, OUTD, Bswc2, (b - 896) * 256 + t);
}

// ---------------- CSR build over seg = dst*8 + etype ----------------
__global__ void hist_kernel(const int* __restrict__ ei, const int* __restrict__ et,
                            int* __restrict__ cnt) {
    int e = blockIdx.x * blockDim.x + threadIdx.x;
    if (e >= NEDGE) return;
    int dst = ei[NEDGE + e];
    int r   = et[e];
    atomicAdd(&cnt[dst * NREL + r], 1);
}

#define SCAN_CHUNK 1024
__global__ void scan1_kernel(int* __restrict__ data, int n, int* __restrict__ bsum) {
    __shared__ int sh[256];
    int t = threadIdx.x;
    int base = blockIdx.x * SCAN_CHUNK + t * 4;
    int v[4];
#pragma unroll
    for (int i = 0; i < 4; i++) v[i] = (base + i < n) ? data[base + i] : 0;
    int tot = v[0] + v[1] + v[2] + v[3];
    sh[t] = tot; __syncthreads();
    for (int off = 1; off < 256; off <<= 1) {
        int x = (t >= off) ? sh[t - off] : 0;
        __syncthreads();
        sh[t] += x;
        __syncthreads();
    }
    int excl = sh[t] - tot;
    if (t == 255) bsum[blockIdx.x] = sh[255];
    int run = excl;
#pragma unroll
    for (int i = 0; i < 4; i++) {
        if (base + i < n) data[base + i] = run;
        run += v[i];
    }
}

__global__ void scan2_kernel(int* __restrict__ bsum, int nb) {
    __shared__ int sh[512];
    int t = threadIdx.x;
    int v = (t < nb) ? bsum[t] : 0;
    sh[t] = v; __syncthreads();
    for (int off = 1; off < 512; off <<= 1) {
        int x = (t >= off) ? sh[t - off] : 0;
        __syncthreads();
        sh[t] += x;
        __syncthreads();
    }
    if (t < nb) bsum[t] = sh[t] - v;
}

// also materializes fill[] (scatter cursor) — drops the d2d memcpy dispatch
__global__ void scan3_kernel(int* __restrict__ data, int n, const int* __restrict__ bsum,
                             int* __restrict__ fill) {
    int add = bsum[blockIdx.x];
    int base = blockIdx.x * SCAN_CHUNK + threadIdx.x * 4;
#pragma unroll
    for (int i = 0; i < 4; i++) {
        int idx = base + i;
        if (idx < n) {
            int v = data[idx] + add;
            data[idx] = v;
            if (idx < NSEG) fill[idx] = v;
        }
    }
}

// packs (src | rel<<16) so agg can walk a node's edges as ONE contiguous run
__global__ void scatter_kernel(const int* __restrict__ ei, const int* __restrict__ et,
                               int* __restrict__ fill, int* __restrict__ epk) {
    int e = blockIdx.x * blockDim.x + threadIdx.x;
    if (e >= NEDGE) return;
    int src = ei[e];
    int dst = ei[NEDGE + e];
    int r   = et[e];
    int pos = atomicAdd(&fill[dst * NREL + r], 1);
    epk[pos] = src | (r << 16);
}

// ---------------- FUSED conv, 16-row M-tile (TLP-preserving) ----------------
// One block = 16 nodes. 4 waves: each wave aggregates 4 nodes (serial) into a
// 16 KB LDS tile, then computes NT/4 column tiles of the 16-row MFMA GEMM.
// vs round-1 (64-row tile): 4x more blocks (3125), 4x less per-wave serial gather,
// 16 KB LDS -> 4 blocks/CU resident (launch_bounds 256,4) = 16 waves/CU with
// 4-deep pipelines each. Per-node (p,e,wl) state hoisted so rowptr loads overlap.
// Extra B traffic (160 KB/block) stays L2-resident (Bsw << 4 MB/XCD).
template<int NT, bool RELU, bool RES>
__global__ __launch_bounds__(256, 4) void fused_conv16(
    const u16* __restrict__ xbf, const float* __restrict__ comp,
    const int* __restrict__ rowptr, const int* __restrict__ epk,
    const u16* __restrict__ Bsw, const float* __restrict__ bias,
    float* __restrict__ out1, u16* __restrict__ outb,
    const float* __restrict__ resid, int ldo) {
    __shared__ u16 As[16 * 512];           // 16 KB: 16 rows x 512 bf16 (4 bases x 128 ch)
    int tid  = threadIdx.x;
    int wv   = __builtin_amdgcn_readfirstlane(tid >> 6);
    int lane = tid & 63;
    int co   = lane * 2;                   // u16 offset within 128-ch row
    float compv = (lane < 32) ? comp[lane] : 0.f;   // lanes >=32 hold 0 (sentinel slot)
    const int INV = 8 << 16;               // sentinel: src=0, rel=8 (zero weight)

    int nbase = blockIdx.x * 16 + wv * 4;  // grid*16 == NNODE exactly; no bounds checks

    // ---- hoisted per-node state: all 4 nodes' rowptr loads issue together ----
    int p[4], e[4];
    float wl[4];                           // lane k<32 holds comp[r][b]*norm(r), r=k>>2, b=k&3
#pragma unroll
    for (int i = 0; i < 4; i++) {
        int rbase = (nbase + i) * NREL;
        float w = 0.f;
        if (lane < 32) {
            int r   = lane >> 2;
            int c0  = rowptr[rbase + r], c1 = rowptr[rbase + r + 1];
            int cnt = c1 - c0;
            w = compv * ((cnt > 0) ? 1.f / (float)cnt : 0.f);
        }
        wl[i] = w;
        p[i] = __builtin_amdgcn_readfirstlane(rowptr[rbase]);
        e[i] = __builtin_amdgcn_readfirstlane(rowptr[rbase + 8]);
    }

    // ---- phase 1: aggregate 4 nodes per wave into LDS ----
#pragma unroll
    for (int i = 0; i < 4; i++) {
        int lr = wv * 4 + i;               // local row in tile
        float a0[4] = {0.f, 0.f, 0.f, 0.f};
        float a1[4] = {0.f, 0.f, 0.f, 0.f};
        int k0[4]; u32 v0[4];
#pragma unroll
        for (int j = 0; j < 4; j++) k0[j] = (p[i] + j < e[i]) ? epk[p[i] + j] : INV;
#pragma unroll
        for (int j = 0; j < 4; j++) v0[j] = *(const u32*)(xbf + ((size_t)(k0[j] & 0xffff) << 7) + co);
        for (int pc = p[i]; pc < e[i]; pc += 4) {
            int pn = pc + 4;
            int k1[4]; u32 v1[4];
#pragma unroll
            for (int j = 0; j < 4; j++) k1[j] = (pn + j < e[i]) ? epk[pn + j] : INV;
#pragma unroll
            for (int j = 0; j < 4; j++) v1[j] = *(const u32*)(xbf + ((size_t)(k1[j] & 0xffff) << 7) + co);
#pragma unroll
            for (int j = 0; j < 4; j++) {
                int ri = __builtin_amdgcn_readfirstlane((k0[j] >> 16) << 2);   // rel uniform per edge
                float w0 = __uint_as_float(__builtin_amdgcn_readlane(__float_as_uint(wl[i]), ri));
                float w1 = __uint_as_float(__builtin_amdgcn_readlane(__float_as_uint(wl[i]), ri + 1));
                float w2 = __uint_as_float(__builtin_amdgcn_readlane(__float_as_uint(wl[i]), ri + 2));
                float w3 = __uint_as_float(__builtin_amdgcn_readlane(__float_as_uint(wl[i]), ri + 3));
                float xl = blo(v0[j]), xh = bhi(v0[j]);
                a0[0] += w0 * xl; a1[0] += w0 * xh;
                a0[1] += w1 * xl; a1[1] += w1 * xh;
                a0[2] += w2 * xl; a1[2] += w2 * xh;
                a0[3] += w3 * xl; a1[3] += w3 * xh;
            }
#pragma unroll
            for (int j = 0; j < 4; j++) { k0[j] = k1[j]; v0[j] = v1[j]; }
        }
        // write row lr: k = b*128 + 2*lane (+1); raw byte = b*256 + lane*4, XOR-swizzled
        u32 swz = (u32)(lr & 7) << 4;
        char* rowp = (char*)As + lr * 1024;
#pragma unroll
        for (int b = 0; b < 4; b++) {
            u32 pk = (u32)f2b(a0[b]) | ((u32)f2b(a1[b]) << 16);
            *(u32*)(rowp + (((u32)(b * 256 + lane * 4)) ^ swz)) = pk;
        }
    }
    __syncthreads();

    // ---- phase 2: [16 x 640] @ [640 x NT*16] MFMA; wave handles NT/4 col tiles ----
    constexpr int NTW = NT / 4;
    int l15 = lane & 15, quad = lane >> 4;
    int rowbase = blockIdx.x * 16;
    int xrow = rowbase + l15;              // always < NNODE
    const u16*  bp   = Bsw + lane * 8;
    const char* arow = (const char*)As + l15 * 1024;
    u32 swz2 = (u32)(l15 & 7) << 4;
    f32x4 acc[NTW];
#pragma unroll
    for (int t = 0; t < NTW; t++) acc[t] = (f32x4){0.f, 0.f, 0.f, 0.f};
#pragma unroll
    for (int ks = 0; ks < 20; ks++) {
        bf16x8 a;
        if (ks < 16) a = *(const bf16x8*)(arow + (((u32)(ks * 64 + quad * 16)) ^ swz2));
        else         a = as_bf(*(const ushort8*)(xbf + (size_t)xrow * 128 + (ks - 16) * 32 + quad * 8));
#pragma unroll
        for (int t = 0; t < NTW; t++) {
            int nt = wv * NTW + t;
            bf16x8 b = as_bf(*(const ushort8*)(bp + ((size_t)(ks * NT + nt) << 9)));
            acc[t] = __builtin_amdgcn_mfma_f32_16x16x32_bf16(a, b, acc[t], 0, 0, 0);
        }
    }
    int orow0 = rowbase + quad * 4;
#pragma unroll
    for (int r = 0; r < 4; r++) {
        int orow = orow0 + r;
#pragma unroll
        for (int t = 0; t < NTW; t++) {
            int col = (wv * NTW + t) * 16 + l15;
            float v = acc[t][r] + bias[col];
            if (RELU) v = v > 0.f ? v : 0.f;
            if (RES)  v += resid[(size_t)orow * ldo + col];
            size_t oi = (size_t)orow * ldo + col;
            if (out1) out1[oi] = v;
            if (outb) outb[oi] = f2b(v);
        }
    }
}

// ---------------- MFMA bf16 GEMM core (projections) ----------------
template<int KMAIN, bool HASX, int NW, int MW, int NT, bool RELU, bool RES, bool AF32>
__device__ __forceinline__ void gemm_core(
    int blk, const void* __restrict__ Av, const u16* __restrict__ xq,
    const u16* __restrict__ Bsw, const float* __restrict__ bias, int M,
    float* __restrict__ out1, float* __restrict__ out2, u16* __restrict__ outb,
    const float* __restrict__ resid, int ldo) {
    constexpr int KSM = KMAIN / 32;
    constexpr int KST = KSM + (HASX ? 4 : 0);
    int tid  = threadIdx.x;
    int wave = tid >> 6, lane = tid & 63;
    int l15  = lane & 15, quad = lane >> 4;
    int rowbase = blk * (NW * MW * 16) + wave * (MW * 16);
    int rA[MW];
#pragma unroll
    for (int m = 0; m < MW; m++) {
        rA[m] = rowbase + m * 16 + l15;
        if (rA[m] > M - 1) rA[m] = M - 1;
    }
    const u16* bp = Bsw + lane * 8;
    f32x4 acc[MW][NT];
#pragma unroll
    for (int m = 0; m < MW; m++)
#pragma unroll
        for (int i = 0; i < NT; i++) acc[m][i] = (f32x4){0.f, 0.f, 0.f, 0.f};
#pragma unroll
    for (int ks = 0; ks < KST; ks++) {
        bf16x8 a[MW];
#pragma unroll
        for (int m = 0; m < MW; m++) {
            if (ks < KSM) {
                if (AF32) a[m] = cvt8((const float*)Av + (size_t)rA[m] * KMAIN + ks * 32 + quad * 8);
                else      a[m] = as_bf(*(const ushort8*)((const u16*)Av + (size_t)rA[m] * KMAIN + ks * 32 + quad * 8));
            } else {
                a[m] = as_bf(*(const ushort8*)(xq + (size_t)rA[m] * 128 + (ks - KSM) * 32 + quad * 8));
            }
        }
#pragma unroll
        for (int nt = 0; nt < NT; nt++) {
            bf16x8 b = as_bf(*(const ushort8*)(bp + ((size_t)(ks * NT + nt) << 9)));
#pragma unroll
            for (int m = 0; m < MW; m++)
                acc[m][nt] = __builtin_amdgcn_mfma_f32_16x16x32_bf16(a[m], b, acc[m][nt], 0, 0, 0);
        }
    }
#pragma unroll
    for (int m = 0; m < MW; m++) {
        int orow0 = rowbase + m * 16 + quad * 4;
#pragma unroll
        for (int r = 0; r < 4; r++) {
            int orow = orow0 + r;
            if (orow < M) {
#pragma unroll
                for (int nt = 0; nt < NT; nt++) {
                    int col = nt * 16 + l15;
                    float v = acc[m][nt][r] + bias[col];
                    if (RELU) v = v > 0.f ? v : 0.f;
                    if (RES)  v += resid[(size_t)orow * ldo + col];
                    size_t oi = (size_t)orow * ldo + col;
                    if (out1) out1[oi] = v;
                    if (out2) out2[oi] = v;
                    if (outb) outb[oi] = f2b(v);
                }
            }
        }
    }
}

// both projections in one dispatch (gridDim.y = 2 selects paper/author)
__global__ __launch_bounds__(256, 2) void proj2_kernel(
    const float* __restrict__ xp, const float* __restrict__ xa,
    const u16* __restrict__ Bswp, const u16* __restrict__ Bswa,
    const float* __restrict__ bp, const float* __restrict__ ba,
    float* __restrict__ lat0, float* __restrict__ lat1, u16* __restrict__ xbf0) {
    int y = blockIdx.y;
    const float* A    = y ? xa : xp;
    const u16*   B    = y ? Bswa : Bswp;
    const float* bias = y ? ba : bp;
    size_t off = (size_t)y * NPER * HIDD;
    gemm_core<256, false, 4, 1, 8, true, false, true>(
        blockIdx.x, A, nullptr, B, bias, NPER, lat0 + off, lat1 + off, xbf0 + off, nullptr, HIDD);
}

extern "C" void kernel_launch(void* const* d_in, const int* in_sizes, int n_in,
                              void* d_out, int out_size, void* d_ws, size_t ws_size,
                              hipStream_t stream) {
    const float* x_paper  = (const float*)d_in[0];
    const float* x_author = (const float*)d_in[1];
    const float* W_paper  = (const float*)d_in[2];
    const float* b_paper  = (const float*)d_in[3];
    const float* W_author = (const float*)d_in[4];
    const float* b_author = (const float*)d_in[5];
    const float* bases0   = (const float*)d_in[6];
    const float* comp0    = (const float*)d_in[7];
    const float* root0    = (const float*)d_in[8];
    const float* bias0    = (const float*)d_in[9];
    const float* bases1   = (const float*)d_in[10];
    const float* comp1    = (const float*)d_in[11];
    const float* root1    = (const float*)d_in[12];
    const float* bias1    = (const float*)d_in[13];
    const float* bases2   = (const float*)d_in[14];
    const float* comp2    = (const float*)d_in[15];
    const float* root2    = (const float*)d_in[16];
    const float* bias2    = (const float*)d_in[17];
    const int* ei         = (const int*)d_in[18];
    const int* et         = (const int*)d_in[19];

    float* ob   = (float*)d_out;
    float* outF = ob;                         // [50000,64]
    float* lat0 = ob + 3200000;               // x0
    float* lat1 = ob + 9600000;               // x0 (copy)
    float* lat2 = ob + 16000000;              // x1

    char* w = (char*)d_ws;
    u16*   xbf0   = (u16*)(w + 51200000);     // 12,800,000
    u16*   xbf1   = (u16*)(w + 64000000);     // 12,800,000
    u16*   Bswc0  = (u16*)(w + 76800000);     // 163,840
    u16*   Bswc1  = (u16*)(w + 76963840);     // 163,840
    u16*   Bswc2  = (u16*)(w + 77127680);     // 81,920
    u16*   Bswp   = (u16*)(w + 77209600);     // 65,536
    u16*   Bswa   = (u16*)(w + 77275136);     // 65,536
    int*   rowptr = (int*)(w + 77340672);     // 400001*4 (pad to 1,600,064)
    int*   fill   = (int*)(w + 78940736);     // 1,600,000
    int*   epk    = (int*)(w + 80540736);     // 2,400,000
    int*   bsum   = (int*)(w + 82940736);     // 2,048

    // ---- all weight repacks, one dispatch ----
    build_bsw_all<<<1056, 256, 0, stream>>>(W_paper, W_author, bases0, root0,
                                            bases1, root1, bases2, root2,
                                            Bswp, Bswa, Bswc0, Bswc1, Bswc2);

    // ---- projections: x0 = relu(x @ W + b) -> lat0, lat1 (fp32) + xbf0 (bf16) ----
    proj2_kernel<<<dim3((NPER + 63) / 64, 2), 256, 0, stream>>>(
        x_paper, x_author, Bswp, Bswa, b_paper, b_author, lat0, lat1, xbf0);

    // ---- CSR over (dst, rel) segments (shared by all 3 convs) ----
    hipMemsetAsync(rowptr, 0, (NSEG + 1) * sizeof(int), stream);
    hist_kernel<<<(NEDGE + 255) / 256, 256, 0, stream>>>(ei, et, rowptr);
    int nchunk = (NSEG + 1 + SCAN_CHUNK - 1) / SCAN_CHUNK;   // 391
    scan1_kernel<<<nchunk, 256, 0, stream>>>(rowptr, NSEG + 1, bsum);
    scan2_kernel<<<1, 512, 0, stream>>>(bsum, nchunk);
    scan3_kernel<<<nchunk, 256, 0, stream>>>(rowptr, NSEG + 1, bsum, fill);
    scatter_kernel<<<(NEDGE + 255) / 256, 256, 0, stream>>>(ei, et, fill, epk);

    int ngrid = NNODE / 16;                   // 3125 blocks, 16 nodes each

    // ---- conv0: x1 = relu(rgcn(x0)) -> lat2 (fp32) + xbf1 (bf16) ----
    fused_conv16<8, true, false><<<ngrid, 256, 0, stream>>>(
        xbf0, comp0, rowptr, epk, Bswc0, bias0, lat2, xbf1, nullptr, HIDD);

    // ---- conv1: x2 = x1 + relu(rgcn(x1)) -> xbf0 (bf16 only; x2 not an output) ----
    fused_conv16<8, true, true><<<ngrid, 256, 0, stream>>>(
        xbf1, comp1, rowptr, epk, Bswc1, bias1, nullptr, xbf0, lat2, HIDD);

    // ---- conv2: out = rgcn(x2) (no relu) -> outF fp32 ----
    fused_conv16<4, false, false><<<ngrid, 256, 0, stream>>>(
        xbf0, comp2, rowptr, epk, Bswc2, bias2, outF, nullptr, nullptr, OUTD);
}

// Round 3
// 388.204 us; speedup vs baseline: 1.4882x; 1.0235x over previous
//
#include <hip/hip_runtime.h>
#include <stdint.h>

#define NPER  25000
#define NNODE 50000
#define NEDGE 600000
#define NREL  8
#define NBASE 4
#define INDIM 256
#define HIDD  128
#define OUTD  64
#define NSEG  (NNODE * NREL)

typedef unsigned short u16;
typedef unsigned int   u32;
typedef __attribute__((ext_vector_type(8))) __bf16          bf16x8;
typedef __attribute__((ext_vector_type(8))) unsigned short  ushort8;
typedef __attribute__((ext_vector_type(4))) float           f32x4;
typedef __attribute__((ext_vector_type(2))) float           f32x2;

__device__ __forceinline__ u16 f2b(float f) {
    union { __bf16 h; u16 u; } v; v.h = (__bf16)f; return v.u;   // HW RNE cvt
}
__device__ __forceinline__ bf16x8 as_bf(ushort8 u) {
    union { ushort8 a; bf16x8 b; } v; v.a = u; return v.b;
}
__device__ __forceinline__ bf16x8 cvt8(const float* p) {
    f32x4 f0 = *(const f32x4*)p;
    f32x4 f1 = *(const f32x4*)(p + 4);
    ushort8 u;
#pragma unroll
    for (int i = 0; i < 4; i++) { u[i] = f2b(f0[i]); u[i + 4] = f2b(f1[i]); }
    return as_bf(u);
}
__device__ __forceinline__ float blo(u32 v) {
    union { u32 i; float f; } u; u.i = v << 16; return u.f;
}
__device__ __forceinline__ float bhi(u32 v) {
    union { u32 i; float f; } u; u.i = v & 0xffff0000u; return u.f;
}

// ---------------- fused weight repack: all 5 Bsw buffers in ONE kernel ----------------
// Bsw[((ks*NT + nt) << 9) + lane*8 + j] = W[k][col],
//   k = ks*32 + (lane>>4)*8 + j, col = nt*16 + (lane&15).
__device__ __forceinline__ void bsw_proj_elem(const float* __restrict__ W, u16* __restrict__ out, int idx) {
    int j    = idx & 7;
    int lane = (idx >> 3) & 63;
    int rest = idx >> 9;
    int nt   = rest & 7;           // 128/16 = 8 col tiles
    int ks   = rest >> 3;
    int col  = nt * 16 + (lane & 15);
    int k    = ks * 32 + ((lane >> 4) << 3) + j;
    out[idx] = f2b(W[(size_t)k * 128 + col]);
}
__device__ __forceinline__ void bsw_conv_elem(const float* __restrict__ bases, const float* __restrict__ root,
                                              int ncol, u16* __restrict__ out, int idx) {
    int nt_cnt = ncol >> 4;
    int j    = idx & 7;
    int lane = (idx >> 3) & 63;
    int rest = idx >> 9;
    int nt   = rest % nt_cnt;
    int ks   = rest / nt_cnt;
    int col  = nt * 16 + (lane & 15);
    int k    = ks * 32 + ((lane >> 4) << 3) + j;
    float v = (k < 512) ? bases[(size_t)k * ncol + col] : root[(size_t)(k - 512) * ncol + col];
    out[idx] = f2b(v);
}
// block ranges: [0,128) Wp | [128,256) Wa | [256,576) conv0 | [576,896) conv1 | [896,1056) conv2
__global__ void build_bsw_all(const float* __restrict__ Wp, const float* __restrict__ Wa,
                              const float* __restrict__ bases0, const float* __restrict__ root0,
                              const float* __restrict__ bases1, const float* __restrict__ root1,
                              const float* __restrict__ bases2, const float* __restrict__ root2,
                              u16* __restrict__ Bswp, u16* __restrict__ Bswa,
                              u16* __restrict__ Bswc0, u16* __restrict__ Bswc1, u16* __restrict__ Bswc2) {
    int b = blockIdx.x, t = threadIdx.x;
    if (b < 128)       bsw_proj_elem(Wp, Bswp, b * 256 + t);
    else if (b < 256)  bsw_proj_elem(Wa, Bswa, (b - 128) * 256 + t);
    else if (b < 576)  bsw_conv_elem(bases0, root0, HIDD, Bswc0, (b - 256) * 256 + t);
    else if (b < 896)  bsw_conv_elem(bases1, root1, HIDD, Bswc1, (b - 576) * 256 + t);
    else               bsw_conv_elem(bases2, root2, OUTD, Bswc2, (b - 896) * 256 + t);
}

// ---------------- CSR build over seg = dst*8 + etype ----------------
__global__ void hist_kernel(const int* __restrict__ ei, const int* __restrict__ et,
                            int* __restrict__ cnt) {
    int e = blockIdx.x * blockDim.x + threadIdx.x;
    if (e >= NEDGE) return;
    int dst = ei[NEDGE + e];
    int r   = et[e];
    atomicAdd(&cnt[dst * NREL + r], 1);
}

#define SCAN_CHUNK 1024
__global__ void scan1_kernel(int* __restrict__ data, int n, int* __restrict__ bsum) {
    __shared__ int sh[256];
    int t = threadIdx.x;
    int base = blockIdx.x * SCAN_CHUNK + t * 4;
    int v[4];
#pragma unroll
    for (int i = 0; i < 4; i++) v[i] = (base + i < n) ? data[base + i] : 0;
    int tot = v[0] + v[1] + v[2] + v[3];
    sh[t] = tot; __syncthreads();
    for (int off = 1; off < 256; off <<= 1) {
        int x = (t >= off) ? sh[t - off] : 0;
        __syncthreads();
        sh[t] += x;
        __syncthreads();
    }
    int excl = sh[t] - tot;
    if (t == 255) bsum[blockIdx.x] = sh[255];
    int run = excl;
#pragma unroll
    for (int i = 0; i < 4; i++) {
        if (base + i < n) data[base + i] = run;
        run += v[i];
    }
}

__global__ void scan2_kernel(int* __restrict__ bsum, int nb) {
    __shared__ int sh[512];
    int t = threadIdx.x;
    int v = (t < nb) ? bsum[t] : 0;
    sh[t] = v; __syncthreads();
    for (int off = 1; off < 512; off <<= 1) {
        int x = (t >= off) ? sh[t - off] : 0;
        __syncthreads();
        sh[t] += x;
        __syncthreads();
    }
    if (t < nb) bsum[t] = sh[t] - v;
}

// also materializes fill[] (scatter cursor) — drops the d2d memcpy dispatch
__global__ void scan3_kernel(int* __restrict__ data, int n, const int* __restrict__ bsum,
                             int* __restrict__ fill) {
    int add = bsum[blockIdx.x];
    int base = blockIdx.x * SCAN_CHUNK + threadIdx.x * 4;
#pragma unroll
    for (int i = 0; i < 4; i++) {
        int idx = base + i;
        if (idx < n) {
            int v = data[idx] + add;
            data[idx] = v;
            if (idx < NSEG) fill[idx] = v;
        }
    }
}

// packs (src | rel<<16) so agg can walk a node's edges as ONE contiguous run
__global__ void scatter_kernel(const int* __restrict__ ei, const int* __restrict__ et,
                               int* __restrict__ fill, int* __restrict__ epk) {
    int e = blockIdx.x * blockDim.x + threadIdx.x;
    if (e >= NEDGE) return;
    int src = ei[e];
    int dst = ei[NEDGE + e];
    int r   = et[e];
    int pos = atomicAdd(&fill[dst * NREL + r], 1);
    epk[pos] = src | (r << 16);
}

// ---------------- FUSED conv, 16-row M-tile, full-occupancy ----------------
// One block = 16 nodes. 4 waves: each wave aggregates 4 nodes into a 16 KB LDS
// tile, then computes NT/4 column tiles of the 16-row MFMA GEMM.
// R3 changes vs R2: (a) __launch_bounds__(256,8): VGPR<=64, 8 blocks/CU resident
// (LDS 18.9 KB < 20 KB budget) = 32 waves/CU for latency hiding; (b) per-edge
// weight broadcast via per-wave LDS table (1 ds_read_b128, same-addr broadcast,
// no barrier needed) instead of 4x v_readlane chain; (c) f32x2 accumulators to
// let the compiler emit v_pk_fma_f32 (packed dual-FMA). Numerics unchanged.
template<int NT, bool RELU, bool RES>
__global__ __launch_bounds__(256, 8) void fused_conv16(
    const u16* __restrict__ xbf, const float* __restrict__ comp,
    const int* __restrict__ rowptr, const int* __restrict__ epk,
    const u16* __restrict__ Bsw, const float* __restrict__ bias,
    float* __restrict__ out1, u16* __restrict__ outb,
    const float* __restrict__ resid, int ldo) {
    __shared__ u16 As[16 * 512];           // 16 KB: 16 rows x 512 bf16 (4 bases x 128 ch)
    __shared__ float wtab[4][4][40];       // [wave][node][rel*4+b]; rel=8 slots are 0
    int tid  = threadIdx.x;
    int wv   = __builtin_amdgcn_readfirstlane(tid >> 6);
    int lane = tid & 63;
    int co   = lane * 2;                   // u16 offset within 128-ch row
    float compv = (lane < 32) ? comp[lane] : 0.f;
    const int INV = 8 << 16;               // sentinel: src=0, rel=8 (zero weight)

    int nbase = blockIdx.x * 16 + wv * 4;  // grid*16 == NNODE exactly; no bounds checks

    // ---- hoisted per-node state: rowptr loads for all 4 nodes issue together;
    //      weight table (comp[r][b] * 1/cnt(r)) filled per wave, read only by this wave ----
    int p[4], e[4];
#pragma unroll
    for (int i = 0; i < 4; i++) {
        int rbase = (nbase + i) * NREL;
        if (lane < 36) {
            float w = 0.f;
            if (lane < 32) {
                int r   = lane >> 2;
                int c0  = rowptr[rbase + r], c1 = rowptr[rbase + r + 1];
                int cnt = c1 - c0;
                w = compv * ((cnt > 0) ? 1.f / (float)cnt : 0.f);
            }
            wtab[wv][i][lane] = w;
        }
        p[i] = __builtin_amdgcn_readfirstlane(rowptr[rbase]);
        e[i] = __builtin_amdgcn_readfirstlane(rowptr[rbase + 8]);
    }

    // ---- phase 1: aggregate 4 nodes per wave into LDS ----
#pragma unroll
    for (int i = 0; i < 4; i++) {
        int lr = wv * 4 + i;               // local row in tile
        const char* wt = (const char*)&wtab[wv][i][0];
        f32x2 av[4];
#pragma unroll
        for (int b = 0; b < 4; b++) av[b] = (f32x2){0.f, 0.f};
        int k0[4]; u32 v0[4];
#pragma unroll
        for (int j = 0; j < 4; j++) k0[j] = (p[i] + j < e[i]) ? epk[p[i] + j] : INV;
#pragma unroll
        for (int j = 0; j < 4; j++) v0[j] = *(const u32*)(xbf + ((size_t)(k0[j] & 0xffff) << 7) + co);
        for (int pc = p[i]; pc < e[i]; pc += 4) {
            int pn = pc + 4;
            int k1[4]; u32 v1[4];
#pragma unroll
            for (int j = 0; j < 4; j++) k1[j] = (pn + j < e[i]) ? epk[pn + j] : INV;
#pragma unroll
            for (int j = 0; j < 4; j++) v1[j] = *(const u32*)(xbf + ((size_t)(k1[j] & 0xffff) << 7) + co);
#pragma unroll
            for (int j = 0; j < 4; j++) {
                // per-edge weights: one 16B LDS broadcast (rel is wave-uniform -> same addr)
                f32x4 w = *(const f32x4*)(wt + (((u32)k0[j] >> 16) << 4));
                f32x2 x2; x2.x = blo(v0[j]); x2.y = bhi(v0[j]);
                av[0] += w[0] * x2;
                av[1] += w[1] * x2;
                av[2] += w[2] * x2;
                av[3] += w[3] * x2;
            }
#pragma unroll
            for (int j = 0; j < 4; j++) { k0[j] = k1[j]; v0[j] = v1[j]; }
        }
        // write row lr: k = b*128 + 2*lane (+1); raw byte = b*256 + lane*4, XOR-swizzled
        u32 swz = (u32)(lr & 7) << 4;
        char* rowp = (char*)As + lr * 1024;
#pragma unroll
        for (int b = 0; b < 4; b++) {
            u32 pk = (u32)f2b(av[b].x) | ((u32)f2b(av[b].y) << 16);
            *(u32*)(rowp + (((u32)(b * 256 + lane * 4)) ^ swz)) = pk;
        }
    }
    __syncthreads();

    // ---- phase 2: [16 x 640] @ [640 x NT*16] MFMA; wave handles NT/4 col tiles ----
    constexpr int NTW = NT / 4;
    int l15 = lane & 15, quad = lane >> 4;
    int rowbase = blockIdx.x * 16;
    int xrow = rowbase + l15;              // always < NNODE
    const u16*  bp   = Bsw + lane * 8;
    const char* arow = (const char*)As + l15 * 1024;
    u32 swz2 = (u32)(l15 & 7) << 4;
    f32x4 acc[NTW];
#pragma unroll
    for (int t = 0; t < NTW; t++) acc[t] = (f32x4){0.f, 0.f, 0.f, 0.f};
#pragma unroll
    for (int ks = 0; ks < 20; ks++) {
        bf16x8 a;
        if (ks < 16) a = *(const bf16x8*)(arow + (((u32)(ks * 64 + quad * 16)) ^ swz2));
        else         a = as_bf(*(const ushort8*)(xbf + (size_t)xrow * 128 + (ks - 16) * 32 + quad * 8));
#pragma unroll
        for (int t = 0; t < NTW; t++) {
            int nt = wv * NTW + t;
            bf16x8 b = as_bf(*(const ushort8*)(bp + ((size_t)(ks * NT + nt) << 9)));
            acc[t] = __builtin_amdgcn_mfma_f32_16x16x32_bf16(a, b, acc[t], 0, 0, 0);
        }
    }
    int orow0 = rowbase + quad * 4;
#pragma unroll
    for (int r = 0; r < 4; r++) {
        int orow = orow0 + r;
#pragma unroll
        for (int t = 0; t < NTW; t++) {
            int col = (wv * NTW + t) * 16 + l15;
            float v = acc[t][r] + bias[col];
            if (RELU) v = v > 0.f ? v : 0.f;
            if (RES)  v += resid[(size_t)orow * ldo + col];
            size_t oi = (size_t)orow * ldo + col;
            if (out1) out1[oi] = v;
            if (outb) outb[oi] = f2b(v);
        }
    }
}

// ---------------- MFMA bf16 GEMM core (projections) ----------------
template<int KMAIN, bool HASX, int NW, int MW, int NT, bool RELU, bool RES, bool AF32>
__device__ __forceinline__ void gemm_core(
    int blk, const void* __restrict__ Av, const u16* __restrict__ xq,
    const u16* __restrict__ Bsw, const float* __restrict__ bias, int M,
    float* __restrict__ out1, float* __restrict__ out2, u16* __restrict__ outb,
    const float* __restrict__ resid, int ldo) {
    constexpr int KSM = KMAIN / 32;
    constexpr int KST = KSM + (HASX ? 4 : 0);
    int tid  = threadIdx.x;
    int wave = tid >> 6, lane = tid & 63;
    int l15  = lane & 15, quad = lane >> 4;
    int rowbase = blk * (NW * MW * 16) + wave * (MW * 16);
    int rA[MW];
#pragma unroll
    for (int m = 0; m < MW; m++) {
        rA[m] = rowbase + m * 16 + l15;
        if (rA[m] > M - 1) rA[m] = M - 1;
    }
    const u16* bp = Bsw + lane * 8;
    f32x4 acc[MW][NT];
#pragma unroll
    for (int m = 0; m < MW; m++)
#pragma unroll
        for (int i = 0; i < NT; i++) acc[m][i] = (f32x4){0.f, 0.f, 0.f, 0.f};
#pragma unroll
    for (int ks = 0; ks < KST; ks++) {
        bf16x8 a[MW];
#pragma unroll
        for (int m = 0; m < MW; m++) {
            if (ks < KSM) {
                if (AF32) a[m] = cvt8((const float*)Av + (size_t)rA[m] * KMAIN + ks * 32 + quad * 8);
                else      a[m] = as_bf(*(const ushort8*)((const u16*)Av + (size_t)rA[m] * KMAIN + ks * 32 + quad * 8));
            } else {
                a[m] = as_bf(*(const ushort8*)(xq + (size_t)rA[m] * 128 + (ks - KSM) * 32 + quad * 8));
            }
        }
#pragma unroll
        for (int nt = 0; nt < NT; nt++) {
            bf16x8 b = as_bf(*(const ushort8*)(bp + ((size_t)(ks * NT + nt) << 9)));
#pragma unroll
            for (int m = 0; m < MW; m++)
                acc[m][nt] = __builtin_amdgcn_mfma_f32_16x16x32_bf16(a[m], b, acc[m][nt], 0, 0, 0);
        }
    }
#pragma unroll
    for (int m = 0; m < MW; m++) {
        int orow0 = rowbase + m * 16 + quad * 4;
#pragma unroll
        for (int r = 0; r < 4; r++) {
            int orow = orow0 + r;
            if (orow < M) {
#pragma unroll
                for (int nt = 0; nt < NT; nt++) {
                    int col = nt * 16 + l15;
                    float v = acc[m][nt][r] + bias[col];
                    if (RELU) v = v > 0.f ? v : 0.f;
                    if (RES)  v += resid[(size_t)orow * ldo + col];
                    size_t oi = (size_t)orow * ldo + col;
                    if (out1) out1[oi] = v;
                    if (out2) out2[oi] = v;
                    if (outb) outb[oi] = f2b(v);
                }
            }
        }
    }
}

// both projections in one dispatch (gridDim.y = 2 selects paper/author)
__global__ __launch_bounds__(256, 2) void proj2_kernel(
    const float* __restrict__ xp, const float* __restrict__ xa,
    const u16* __restrict__ Bswp, const u16* __restrict__ Bswa,
    const float* __restrict__ bp, const float* __restrict__ ba,
    float* __restrict__ lat0, float* __restrict__ lat1, u16* __restrict__ xbf0) {
    int y = blockIdx.y;
    const float* A    = y ? xa : xp;
    const u16*   B    = y ? Bswa : Bswp;
    const float* bias = y ? ba : bp;
    size_t off = (size_t)y * NPER * HIDD;
    gemm_core<256, false, 4, 1, 8, true, false, true>(
        blockIdx.x, A, nullptr, B, bias, NPER, lat0 + off, lat1 + off, xbf0 + off, nullptr, HIDD);
}

extern "C" void kernel_launch(void* const* d_in, const int* in_sizes, int n_in,
                              void* d_out, int out_size, void* d_ws, size_t ws_size,
                              hipStream_t stream) {
    const float* x_paper  = (const float*)d_in[0];
    const float* x_author = (const float*)d_in[1];
    const float* W_paper  = (const float*)d_in[2];
    const float* b_paper  = (const float*)d_in[3];
    const float* W_author = (const float*)d_in[4];
    const float* b_author = (const float*)d_in[5];
    const float* bases0   = (const float*)d_in[6];
    const float* comp0    = (const float*)d_in[7];
    const float* root0    = (const float*)d_in[8];
    const float* bias0    = (const float*)d_in[9];
    const float* bases1   = (const float*)d_in[10];
    const float* comp1    = (const float*)d_in[11];
    const float* root1    = (const float*)d_in[12];
    const float* bias1    = (const float*)d_in[13];
    const float* bases2   = (const float*)d_in[14];
    const float* comp2    = (const float*)d_in[15];
    const float* root2    = (const float*)d_in[16];
    const float* bias2    = (const float*)d_in[17];
    const int* ei         = (const int*)d_in[18];
    const int* et         = (const int*)d_in[19];

    float* ob   = (float*)d_out;
    float* outF = ob;                         // [50000,64]
    float* lat0 = ob + 3200000;               // x0
    float* lat1 = ob + 9600000;               // x0 (copy)
    float* lat2 = ob + 16000000;              // x1

    char* w = (char*)d_ws;
    u16*   xbf0   = (u16*)(w + 51200000);     // 12,800,000
    u16*   xbf1   = (u16*)(w + 64000000);     // 12,800,000
    u16*   Bswc0  = (u16*)(w + 76800000);     // 163,840
    u16*   Bswc1  = (u16*)(w + 76963840);     // 163,840
    u16*   Bswc2  = (u16*)(w + 77127680);     // 81,920
    u16*   Bswp   = (u16*)(w + 77209600);     // 65,536
    u16*   Bswa   = (u16*)(w + 77275136);     // 65,536
    int*   rowptr = (int*)(w + 77340672);     // 400001*4 (pad to 1,600,064)
    int*   fill   = (int*)(w + 78940736);     // 1,600,000
    int*   epk    = (int*)(w + 80540736);     // 2,400,000
    int*   bsum   = (int*)(w + 82940736);     // 2,048

    // ---- all weight repacks, one dispatch ----
    build_bsw_all<<<1056, 256, 0, stream>>>(W_paper, W_author, bases0, root0,
                                            bases1, root1, bases2, root2,
                                            Bswp, Bswa, Bswc0, Bswc1, Bswc2);

    // ---- projections: x0 = relu(x @ W + b) -> lat0, lat1 (fp32) + xbf0 (bf16) ----
    proj2_kernel<<<dim3((NPER + 63) / 64, 2), 256, 0, stream>>>(
        x_paper, x_author, Bswp, Bswa, b_paper, b_author, lat0, lat1, xbf0);

    // ---- CSR over (dst, rel) segments (shared by all 3 convs) ----
    hipMemsetAsync(rowptr, 0, (NSEG + 1) * sizeof(int), stream);
    hist_kernel<<<(NEDGE + 255) / 256, 256, 0, stream>>>(ei, et, rowptr);
    int nchunk = (NSEG + 1 + SCAN_CHUNK - 1) / SCAN_CHUNK;   // 391
    scan1_kernel<<<nchunk, 256, 0, stream>>>(rowptr, NSEG + 1, bsum);
    scan2_kernel<<<1, 512, 0, stream>>>(bsum, nchunk);
    scan3_kernel<<<nchunk, 256, 0, stream>>>(rowptr, NSEG + 1, bsum, fill);
    scatter_kernel<<<(NEDGE + 255) / 256, 256, 0, stream>>>(ei, et, fill, epk);

    int ngrid = NNODE / 16;                   // 3125 blocks, 16 nodes each

    // ---- conv0: x1 = relu(rgcn(x0)) -> lat2 (fp32) + xbf1 (bf16) ----
    fused_conv16<8, true, false><<<ngrid, 256, 0, stream>>>(
        xbf0, comp0, rowptr, epk, Bswc0, bias0, lat2, xbf1, nullptr, HIDD);

    // ---- conv1: x2 = x1 + relu(rgcn(x1)) -> xbf0 (bf16 only; x2 not an output) ----
    fused_conv16<8, true, true><<<ngrid, 256, 0, stream>>>(
        xbf1, comp1, rowptr, epk, Bswc1, bias1, nullptr, xbf0, lat2, HIDD);

    // ---- conv2: out = rgcn(x2) (no relu) -> outF fp32 ----
    fused_conv16<4, false, false><<<ngrid, 256, 0, stream>>>(
        xbf0, comp2, rowptr, epk, Bswc2, bias2, outF, nullptr, nullptr, OUTD);
}

// Round 4
// 379.135 us; speedup vs baseline: 1.5238x; 1.0239x over previous
//
#include <hip/hip_runtime.h>
#include <stdint.h>

#define NPER  25000
#define NNODE 50000
#define NEDGE 600000
#define NREL  8
#define NBASE 4
#define INDIM 256
#define HIDD  128
#define OUTD  64
#define NSEG  (NNODE * NREL)

typedef unsigned short u16;
typedef unsigned int   u32;
typedef __attribute__((ext_vector_type(8))) __bf16          bf16x8;
typedef __attribute__((ext_vector_type(8))) unsigned short  ushort8;
typedef __attribute__((ext_vector_type(4))) float           f32x4;
typedef __attribute__((ext_vector_type(2))) float           f32x2;

__device__ __forceinline__ u16 f2b(float f) {
    union { __bf16 h; u16 u; } v; v.h = (__bf16)f; return v.u;   // HW RNE cvt
}
__device__ __forceinline__ bf16x8 as_bf(ushort8 u) {
    union { ushort8 a; bf16x8 b; } v; v.a = u; return v.b;
}
__device__ __forceinline__ bf16x8 cvt8(const float* p) {
    f32x4 f0 = *(const f32x4*)p;
    f32x4 f1 = *(const f32x4*)(p + 4);
    ushort8 u;
#pragma unroll
    for (int i = 0; i < 4; i++) { u[i] = f2b(f0[i]); u[i + 4] = f2b(f1[i]); }
    return as_bf(u);
}
__device__ __forceinline__ float blo(u32 v) {
    union { u32 i; float f; } u; u.i = v << 16; return u.f;
}
__device__ __forceinline__ float bhi(u32 v) {
    union { u32 i; float f; } u; u.i = v & 0xffff0000u; return u.f;
}

// ---------------- fused weight repack: all 5 Bsw buffers in ONE kernel ----------------
// Bsw[((ks*NT + nt) << 9) + lane*8 + j] = W[k][col],
//   k = ks*32 + (lane>>4)*8 + j, col = nt*16 + (lane&15).
__device__ __forceinline__ void bsw_proj_elem(const float* __restrict__ W, u16* __restrict__ out, int idx) {
    int j    = idx & 7;
    int lane = (idx >> 3) & 63;
    int rest = idx >> 9;
    int nt   = rest & 7;           // 128/16 = 8 col tiles
    int ks   = rest >> 3;
    int col  = nt * 16 + (lane & 15);
    int k    = ks * 32 + ((lane >> 4) << 3) + j;
    out[idx] = f2b(W[(size_t)k * 128 + col]);
}
__device__ __forceinline__ void bsw_conv_elem(const float* __restrict__ bases, const float* __restrict__ root,
                                              int ncol, u16* __restrict__ out, int idx) {
    int nt_cnt = ncol >> 4;
    int j    = idx & 7;
    int lane = (idx >> 3) & 63;
    int rest = idx >> 9;
    int nt   = rest % nt_cnt;
    int ks   = rest / nt_cnt;
    int col  = nt * 16 + (lane & 15);
    int k    = ks * 32 + ((lane >> 4) << 3) + j;
    float v = (k < 512) ? bases[(size_t)k * ncol + col] : root[(size_t)(k - 512) * ncol + col];
    out[idx] = f2b(v);
}
// block ranges: [0,128) Wp | [128,256) Wa | [256,576) conv0 | [576,896) conv1 | [896,1056) conv2
__global__ void build_bsw_all(const float* __restrict__ Wp, const float* __restrict__ Wa,
                              const float* __restrict__ bases0, const float* __restrict__ root0,
                              const float* __restrict__ bases1, const float* __restrict__ root1,
                              const float* __restrict__ bases2, const float* __restrict__ root2,
                              u16* __restrict__ Bswp, u16* __restrict__ Bswa,
                              u16* __restrict__ Bswc0, u16* __restrict__ Bswc1, u16* __restrict__ Bswc2) {
    int b = blockIdx.x, t = threadIdx.x;
    if (b < 128)       bsw_proj_elem(Wp, Bswp, b * 256 + t);
    else if (b < 256)  bsw_proj_elem(Wa, Bswa, (b - 128) * 256 + t);
    else if (b < 576)  bsw_conv_elem(bases0, root0, HIDD, Bswc0, (b - 256) * 256 + t);
    else if (b < 896)  bsw_conv_elem(bases1, root1, HIDD, Bswc1, (b - 576) * 256 + t);
    else               bsw_conv_elem(bases2, root2, OUTD, Bswc2, (b - 896) * 256 + t);
}

// ---------------- CSR build over seg = dst*8 + etype ----------------
__global__ void hist_kernel(const int* __restrict__ ei, const int* __restrict__ et,
                            int* __restrict__ cnt) {
    int e = blockIdx.x * blockDim.x + threadIdx.x;
    if (e >= NEDGE) return;
    int dst = ei[NEDGE + e];
    int r   = et[e];
    atomicAdd(&cnt[dst * NREL + r], 1);
}

#define SCAN_CHUNK 1024
__global__ void scan1_kernel(int* __restrict__ data, int n, int* __restrict__ bsum) {
    __shared__ int sh[256];
    int t = threadIdx.x;
    int base = blockIdx.x * SCAN_CHUNK + t * 4;
    int v[4];
#pragma unroll
    for (int i = 0; i < 4; i++) v[i] = (base + i < n) ? data[base + i] : 0;
    int tot = v[0] + v[1] + v[2] + v[3];
    sh[t] = tot; __syncthreads();
    for (int off = 1; off < 256; off <<= 1) {
        int x = (t >= off) ? sh[t - off] : 0;
        __syncthreads();
        sh[t] += x;
        __syncthreads();
    }
    int excl = sh[t] - tot;
    if (t == 255) bsum[blockIdx.x] = sh[255];
    int run = excl;
#pragma unroll
    for (int i = 0; i < 4; i++) {
        if (base + i < n) data[base + i] = run;
        run += v[i];
    }
}

__global__ void scan2_kernel(int* __restrict__ bsum, int nb) {
    __shared__ int sh[512];
    int t = threadIdx.x;
    int v = (t < nb) ? bsum[t] : 0;
    sh[t] = v; __syncthreads();
    for (int off = 1; off < 512; off <<= 1) {
        int x = (t >= off) ? sh[t - off] : 0;
        __syncthreads();
        sh[t] += x;
        __syncthreads();
    }
    if (t < nb) bsum[t] = sh[t] - v;
}

// also materializes fill[] (scatter cursor) — drops the d2d memcpy dispatch
__global__ void scan3_kernel(int* __restrict__ data, int n, const int* __restrict__ bsum,
                             int* __restrict__ fill) {
    int add = bsum[blockIdx.x];
    int base = blockIdx.x * SCAN_CHUNK + threadIdx.x * 4;
#pragma unroll
    for (int i = 0; i < 4; i++) {
        int idx = base + i;
        if (idx < n) {
            int v = data[idx] + add;
            data[idx] = v;
            if (idx < NSEG) fill[idx] = v;
        }
    }
}

// packs (src | rel<<16) so agg can walk a node's edges as ONE contiguous run
__global__ void scatter_kernel(const int* __restrict__ ei, const int* __restrict__ et,
                               int* __restrict__ fill, int* __restrict__ epk) {
    int e = blockIdx.x * blockDim.x + threadIdx.x;
    if (e >= NEDGE) return;
    int src = ei[e];
    int dst = ei[NEDGE + e];
    int r   = et[e];
    int pos = atomicAdd(&fill[dst * NREL + r], 1);
    epk[pos] = src | (r << 16);
}

// ---------------- FUSED conv, 16-row M-tile, 8-deep gather pipeline ----------------
// One block = 16 nodes. 4 waves: each wave aggregates 4 nodes into a 16 KB LDS
// tile, then computes NT/4 column tiles of the 16-row MFMA GEMM.
// R4 change vs R3: gather walk deepened 4 -> 8 edges per pipeline stage
// (16 VMEM in flight per wave instead of 8) — the conv is latency-bound
// (MfmaUtil 6 / VALUBusy 34 / HBM 22 / occ 60, all low) and occupancy is at its
// structural cap, so per-wave MLP is the only remaining latency-hiding lever.
// Per-edge accumulate order unchanged (ascending epk position) -> bit-identical.
template<int NT, bool RELU, bool RES>
__global__ __launch_bounds__(256, 8) void fused_conv16(
    const u16* __restrict__ xbf, const float* __restrict__ comp,
    const int* __restrict__ rowptr, const int* __restrict__ epk,
    const u16* __restrict__ Bsw, const float* __restrict__ bias,
    float* __restrict__ out1, u16* __restrict__ outb,
    const float* __restrict__ resid, int ldo) {
    __shared__ u16 As[16 * 512];           // 16 KB: 16 rows x 512 bf16 (4 bases x 128 ch)
    __shared__ float wtab[4][4][40];       // [wave][node][rel*4+b]; rel=8 slots are 0
    int tid  = threadIdx.x;
    int wv   = __builtin_amdgcn_readfirstlane(tid >> 6);
    int lane = tid & 63;
    int co   = lane * 2;                   // u16 offset within 128-ch row
    float compv = (lane < 32) ? comp[lane] : 0.f;
    const int INV = 8 << 16;               // sentinel: src=0, rel=8 (zero weight)
    const u16* xco = xbf + co;

    int nbase = blockIdx.x * 16 + wv * 4;  // grid*16 == NNODE exactly; no bounds checks

    // ---- hoisted per-node state: rowptr loads for all 4 nodes issue together;
    //      weight table (comp[r][b] * 1/cnt(r)) filled per wave, read only by this wave ----
    int p[4], e[4];
#pragma unroll
    for (int i = 0; i < 4; i++) {
        int rbase = (nbase + i) * NREL;
        if (lane < 36) {
            float w = 0.f;
            if (lane < 32) {
                int r   = lane >> 2;
                int c0  = rowptr[rbase + r], c1 = rowptr[rbase + r + 1];
                int cnt = c1 - c0;
                w = compv * ((cnt > 0) ? 1.f / (float)cnt : 0.f);
            }
            wtab[wv][i][lane] = w;
        }
        p[i] = __builtin_amdgcn_readfirstlane(rowptr[rbase]);
        e[i] = __builtin_amdgcn_readfirstlane(rowptr[rbase + 8]);
    }

    // ---- phase 1: aggregate 4 nodes per wave into LDS (8-deep pipelined walk) ----
#pragma unroll
    for (int i = 0; i < 4; i++) {
        int lr = wv * 4 + i;               // local row in tile
        const char* wt = (const char*)&wtab[wv][i][0];
        f32x2 av[4];
#pragma unroll
        for (int b = 0; b < 4; b++) av[b] = (f32x2){0.f, 0.f};
        int k0[8]; u32 v0[8];
#pragma unroll
        for (int j = 0; j < 8; j++) k0[j] = (p[i] + j < e[i]) ? epk[p[i] + j] : INV;
#pragma unroll
        for (int j = 0; j < 8; j++) v0[j] = *(const u32*)(xco + ((size_t)(k0[j] & 0xffff) << 7));
        for (int pc = p[i]; pc < e[i]; pc += 8) {
            int pn = pc + 8;
            int k1[8]; u32 v1[8];
#pragma unroll
            for (int j = 0; j < 8; j++) k1[j] = (pn + j < e[i]) ? epk[pn + j] : INV;
#pragma unroll
            for (int j = 0; j < 8; j++) v1[j] = *(const u32*)(xco + ((size_t)(k1[j] & 0xffff) << 7));
#pragma unroll
            for (int j = 0; j < 8; j++) {
                // per-edge weights: one 16B LDS broadcast (rel is wave-uniform -> same addr)
                f32x4 w = *(const f32x4*)(wt + (((u32)k0[j] >> 16) << 4));
                f32x2 x2; x2.x = blo(v0[j]); x2.y = bhi(v0[j]);
                av[0] += w[0] * x2;
                av[1] += w[1] * x2;
                av[2] += w[2] * x2;
                av[3] += w[3] * x2;
            }
#pragma unroll
            for (int j = 0; j < 8; j++) { k0[j] = k1[j]; v0[j] = v1[j]; }
        }
        // write row lr: k = b*128 + 2*lane (+1); raw byte = b*256 + lane*4, XOR-swizzled
        u32 swz = (u32)(lr & 7) << 4;
        char* rowp = (char*)As + lr * 1024;
#pragma unroll
        for (int b = 0; b < 4; b++) {
            u32 pk = (u32)f2b(av[b].x) | ((u32)f2b(av[b].y) << 16);
            *(u32*)(rowp + (((u32)(b * 256 + lane * 4)) ^ swz)) = pk;
        }
    }
    __syncthreads();

    // ---- phase 2: [16 x 640] @ [640 x NT*16] MFMA; wave handles NT/4 col tiles ----
    constexpr int NTW = NT / 4;
    int l15 = lane & 15, quad = lane >> 4;
    int rowbase = blockIdx.x * 16;
    int xrow = rowbase + l15;              // always < NNODE
    const u16*  bp   = Bsw + lane * 8;
    const char* arow = (const char*)As + l15 * 1024;
    u32 swz2 = (u32)(l15 & 7) << 4;
    f32x4 acc[NTW];
#pragma unroll
    for (int t = 0; t < NTW; t++) acc[t] = (f32x4){0.f, 0.f, 0.f, 0.f};
#pragma unroll
    for (int ks = 0; ks < 20; ks++) {
        bf16x8 a;
        if (ks < 16) a = *(const bf16x8*)(arow + (((u32)(ks * 64 + quad * 16)) ^ swz2));
        else         a = as_bf(*(const ushort8*)(xbf + (size_t)xrow * 128 + (ks - 16) * 32 + quad * 8));
#pragma unroll
        for (int t = 0; t < NTW; t++) {
            int nt = wv * NTW + t;
            bf16x8 b = as_bf(*(const ushort8*)(bp + ((size_t)(ks * NT + nt) << 9)));
            acc[t] = __builtin_amdgcn_mfma_f32_16x16x32_bf16(a, b, acc[t], 0, 0, 0);
        }
    }
    int orow0 = rowbase + quad * 4;
#pragma unroll
    for (int r = 0; r < 4; r++) {
        int orow = orow0 + r;
#pragma unroll
        for (int t = 0; t < NTW; t++) {
            int col = (wv * NTW + t) * 16 + l15;
            float v = acc[t][r] + bias[col];
            if (RELU) v = v > 0.f ? v : 0.f;
            if (RES)  v += resid[(size_t)orow * ldo + col];
            size_t oi = (size_t)orow * ldo + col;
            if (out1) out1[oi] = v;
            if (outb) outb[oi] = f2b(v);
        }
    }
}

// ---------------- MFMA bf16 GEMM core (projections) ----------------
template<int KMAIN, bool HASX, int NW, int MW, int NT, bool RELU, bool RES, bool AF32>
__device__ __forceinline__ void gemm_core(
    int blk, const void* __restrict__ Av, const u16* __restrict__ xq,
    const u16* __restrict__ Bsw, const float* __restrict__ bias, int M,
    float* __restrict__ out1, float* __restrict__ out2, u16* __restrict__ outb,
    const float* __restrict__ resid, int ldo) {
    constexpr int KSM = KMAIN / 32;
    constexpr int KST = KSM + (HASX ? 4 : 0);
    int tid  = threadIdx.x;
    int wave = tid >> 6, lane = tid & 63;
    int l15  = lane & 15, quad = lane >> 4;
    int rowbase = blk * (NW * MW * 16) + wave * (MW * 16);
    int rA[MW];
#pragma unroll
    for (int m = 0; m < MW; m++) {
        rA[m] = rowbase + m * 16 + l15;
        if (rA[m] > M - 1) rA[m] = M - 1;
    }
    const u16* bp = Bsw + lane * 8;
    f32x4 acc[MW][NT];
#pragma unroll
    for (int m = 0; m < MW; m++)
#pragma unroll
        for (int i = 0; i < NT; i++) acc[m][i] = (f32x4){0.f, 0.f, 0.f, 0.f};
#pragma unroll
    for (int ks = 0; ks < KST; ks++) {
        bf16x8 a[MW];
#pragma unroll
        for (int m = 0; m < MW; m++) {
            if (ks < KSM) {
                if (AF32) a[m] = cvt8((const float*)Av + (size_t)rA[m] * KMAIN + ks * 32 + quad * 8);
                else      a[m] = as_bf(*(const ushort8*)((const u16*)Av + (size_t)rA[m] * KMAIN + ks * 32 + quad * 8));
            } else {
                a[m] = as_bf(*(const ushort8*)(xq + (size_t)rA[m] * 128 + (ks - KSM) * 32 + quad * 8));
            }
        }
#pragma unroll
        for (int nt = 0; nt < NT; nt++) {
            bf16x8 b = as_bf(*(const ushort8*)(bp + ((size_t)(ks * NT + nt) << 9)));
#pragma unroll
            for (int m = 0; m < MW; m++)
                acc[m][nt] = __builtin_amdgcn_mfma_f32_16x16x32_bf16(a[m], b, acc[m][nt], 0, 0, 0);
        }
    }
#pragma unroll
    for (int m = 0; m < MW; m++) {
        int orow0 = rowbase + m * 16 + quad * 4;
#pragma unroll
        for (int r = 0; r < 4; r++) {
            int orow = orow0 + r;
            if (orow < M) {
#pragma unroll
                for (int nt = 0; nt < NT; nt++) {
                    int col = nt * 16 + l15;
                    float v = acc[m][nt][r] + bias[col];
                    if (RELU) v = v > 0.f ? v : 0.f;
                    if (RES)  v += resid[(size_t)orow * ldo + col];
                    size_t oi = (size_t)orow * ldo + col;
                    if (out1) out1[oi] = v;
                    if (out2) out2[oi] = v;
                    if (outb) outb[oi] = f2b(v);
                }
            }
        }
    }
}

// both projections in one dispatch (gridDim.y = 2 selects paper/author)
__global__ __launch_bounds__(256, 2) void proj2_kernel(
    const float* __restrict__ xp, const float* __restrict__ xa,
    const u16* __restrict__ Bswp, const u16* __restrict__ Bswa,
    const float* __restrict__ bp, const float* __restrict__ ba,
    float* __restrict__ lat0, float* __restrict__ lat1, u16* __restrict__ xbf0) {
    int y = blockIdx.y;
    const float* A    = y ? xa : xp;
    const u16*   B    = y ? Bswa : Bswp;
    const float* bias = y ? ba : bp;
    size_t off = (size_t)y * NPER * HIDD;
    gemm_core<256, false, 4, 1, 8, true, false, true>(
        blockIdx.x, A, nullptr, B, bias, NPER, lat0 + off, lat1 + off, xbf0 + off, nullptr, HIDD);
}

extern "C" void kernel_launch(void* const* d_in, const int* in_sizes, int n_in,
                              void* d_out, int out_size, void* d_ws, size_t ws_size,
                              hipStream_t stream) {
    const float* x_paper  = (const float*)d_in[0];
    const float* x_author = (const float*)d_in[1];
    const float* W_paper  = (const float*)d_in[2];
    const float* b_paper  = (const float*)d_in[3];
    const float* W_author = (const float*)d_in[4];
    const float* b_author = (const float*)d_in[5];
    const float* bases0   = (const float*)d_in[6];
    const float* comp0    = (const float*)d_in[7];
    const float* root0    = (const float*)d_in[8];
    const float* bias0    = (const float*)d_in[9];
    const float* bases1   = (const float*)d_in[10];
    const float* comp1    = (const float*)d_in[11];
    const float* root1    = (const float*)d_in[12];
    const float* bias1    = (const float*)d_in[13];
    const float* bases2   = (const float*)d_in[14];
    const float* comp2    = (const float*)d_in[15];
    const float* root2    = (const float*)d_in[16];
    const float* bias2    = (const float*)d_in[17];
    const int* ei         = (const int*)d_in[18];
    const int* et         = (const int*)d_in[19];

    float* ob   = (float*)d_out;
    float* outF = ob;                         // [50000,64]
    float* lat0 = ob + 3200000;               // x0
    float* lat1 = ob + 9600000;               // x0 (copy)
    float* lat2 = ob + 16000000;              // x1

    char* w = (char*)d_ws;
    u16*   xbf0   = (u16*)(w + 51200000);     // 12,800,000
    u16*   xbf1   = (u16*)(w + 64000000);     // 12,800,000
    u16*   Bswc0  = (u16*)(w + 76800000);     // 163,840
    u16*   Bswc1  = (u16*)(w + 76963840);     // 163,840
    u16*   Bswc2  = (u16*)(w + 77127680);     // 81,920
    u16*   Bswp   = (u16*)(w + 77209600);     // 65,536
    u16*   Bswa   = (u16*)(w + 77275136);     // 65,536
    int*   rowptr = (int*)(w + 77340672);     // 400001*4 (pad to 1,600,064)
    int*   fill   = (int*)(w + 78940736);     // 1,600,000
    int*   epk    = (int*)(w + 80540736);     // 2,400,000
    int*   bsum   = (int*)(w + 82940736);     // 2,048

    // ---- all weight repacks, one dispatch ----
    build_bsw_all<<<1056, 256, 0, stream>>>(W_paper, W_author, bases0, root0,
                                            bases1, root1, bases2, root2,
                                            Bswp, Bswa, Bswc0, Bswc1, Bswc2);

    // ---- projections: x0 = relu(x @ W + b) -> lat0, lat1 (fp32) + xbf0 (bf16) ----
    proj2_kernel<<<dim3((NPER + 63) / 64, 2), 256, 0, stream>>>(
        x_paper, x_author, Bswp, Bswa, b_paper, b_author, lat0, lat1, xbf0);

    // ---- CSR over (dst, rel) segments (shared by all 3 convs) ----
    hipMemsetAsync(rowptr, 0, (NSEG + 1) * sizeof(int), stream);
    hist_kernel<<<(NEDGE + 255) / 256, 256, 0, stream>>>(ei, et, rowptr);
    int nchunk = (NSEG + 1 + SCAN_CHUNK - 1) / SCAN_CHUNK;   // 391
    scan1_kernel<<<nchunk, 256, 0, stream>>>(rowptr, NSEG + 1, bsum);
    scan2_kernel<<<1, 512, 0, stream>>>(bsum, nchunk);
    scan3_kernel<<<nchunk, 256, 0, stream>>>(rowptr, NSEG + 1, bsum, fill);
    scatter_kernel<<<(NEDGE + 255) / 256, 256, 0, stream>>>(ei, et, fill, epk);

    int ngrid = NNODE / 16;                   // 3125 blocks, 16 nodes each

    // ---- conv0: x1 = relu(rgcn(x0)) -> lat2 (fp32) + xbf1 (bf16) ----
    fused_conv16<8, true, false><<<ngrid, 256, 0, stream>>>(
        xbf0, comp0, rowptr, epk, Bswc0, bias0, lat2, xbf1, nullptr, HIDD);

    // ---- conv1: x2 = x1 + relu(rgcn(x1)) -> xbf0 (bf16 only; x2 not an output) ----
    fused_conv16<8, true, true><<<ngrid, 256, 0, stream>>>(
        xbf1, comp1, rowptr, epk, Bswc1, bias1, nullptr, xbf0, lat2, HIDD);

    // ---- conv2: out = rgcn(x2) (no relu) -> outF fp32 ----
    fused_conv16<4, false, false><<<ngrid, 256, 0, stream>>>(
        xbf0, comp2, rowptr, epk, Bswc2, bias2, outF, nullptr, nullptr, OUTD);
}